// Round 4
// baseline (216.864 us; speedup 1.0000x reference)
//
#include <hip/hip_runtime.h>
#include <hip/hip_bf16.h>
#include <cstdint>
#include <cstddef>

// Problem constants
#define B_    16
#define CIN   960
#define HH    56
#define WW_   56
#define GG    2
#define COUT  96
#define NK_   5
#define PIX   3136   // 56*56

// Workspace layout (in floats):
//   wb   (bf16 [96][960])  : float idx [0, 46080)
//   bias (f32 [96])        : float idx [46080, 46176)
//   yb16 (bf16 [16][96][3136]) : float idx [46208, 46208+2408448)
#define WB_OFF   0
#define BIAS_OFF 46080
#define Y_OFF    46208

typedef __attribute__((ext_vector_type(8))) short bf16x8;
typedef __attribute__((ext_vector_type(4))) float f32x4;

// fp32 -> bf16 (RNE)
__device__ __forceinline__ short f2b(float f) {
    union { float f; unsigned u; } c; c.f = f;
    unsigned r = (c.u + 0x7FFFu + ((c.u >> 16) & 1u)) >> 16;
    return (short)r;
}
// bf16 bits -> fp32
__device__ __forceinline__ float b2f(short s) {
    union { unsigned u; float f; } c;
    c.u = ((unsigned)(unsigned short)s) << 16;
    return c.f;
}

#define GLOAD_LDS16(gp, lp)                                                        \
    __builtin_amdgcn_global_load_lds(                                              \
        (const __attribute__((address_space(1))) unsigned*)(gp),                   \
        (__attribute__((address_space(3))) unsigned*)(lp), 16, 0, 0)

// ---------------------------------------------------------------------------
// K0a: wb[o][c] = bf16( proj_w[o][c] * (scale[c] + 1e-5) )
__global__ void prep_wb(const float* __restrict__ pw, const float* __restrict__ sc,
                        short* __restrict__ wb) {
    int idx = blockIdx.x * 256 + threadIdx.x;   // o*960 + c
    if (idx >= COUT * CIN) return;
    int c = idx % CIN;
    wb[idx] = f2b(pw[idx] * (sc[c] + 1e-5f));
}

// K0b: bias_o[o] = sum_c proj_w[o][c] * local_bias[c]
__global__ void prep_bias(const float* __restrict__ pw, const float* __restrict__ bi,
                          float* __restrict__ bias) {
    int o = threadIdx.x;
    if (o >= COUT) return;
    float s = 0.f;
    for (int c = 0; c < CIN; ++c) s += pw[o * CIN + c] * bi[c];
    bias[o] = s;
}

// ---------------------------------------------------------------------------
// K1: y[b,o,px] = bias_o + sum_c W[o][c]*x[b,c,px]  (pure GEMM, y written bf16)
// Block: 256 thr / 4 waves, tile 64 px x 96 out. Grid 49 x 16 (all co-resident).
// Staging: global_load_lds width-16 of fp32 x into [32ch][64px] LDS, dbuf,
//          one barrier per chunk. px4-blocks XOR-swizzled by (ch>>3) so the
//          4 kb-groups of the fragment read hit disjoint bank halves.
__global__ __launch_bounds__(256)
void conv_mfma(const float* __restrict__ x, const short* __restrict__ wb,
               const float* __restrict__ bias, short* __restrict__ yb) {
    const int tid  = threadIdx.x;
    const int lane = tid & 63;
    const int wv   = tid >> 6;
    const int b    = blockIdx.y;
    const int px0  = blockIdx.x * 64;

    __shared__ __align__(16) char xs[2][8192];   // [32ch][64px] fp32, double buf

    const float* xbase = x + (size_t)b * CIN * PIX + px0;

    // compute role
    const int pxl = wv * 16 + (lane & 15);   // local pixel 0..63
    const int kb  = lane >> 4;               // k-block 0..3
    const int rbase = (pxl * 4) ^ (kb << 6); // swizzled byte offset within row space
    const short* const wp = wb + (size_t)(lane & 15) * CIN + kb * 8;

    f32x4 acc[6];
#pragma unroll
    for (int f = 0; f < 6; ++f) acc[f] = (f32x4){0.f, 0.f, 0.f, 0.f};

    // stage one 32-ch chunk (8 KB) : 8 instrs, 2 per wave
#define STAGE(bufp, c0)                                                          \
    {                                                                            \
        _Pragma("unroll")                                                        \
        for (int q = 0; q < 2; ++q) {                                            \
            const int i_  = wv * 2 + q;                                          \
            const int ch_ = (c0) + i_ * 4 + (lane >> 4);                         \
            const int px4 = (lane & 15) ^ (((i_ >> 1) & 3) << 2);                \
            GLOAD_LDS16(xbase + (size_t)ch_ * PIX + px4 * 4,                     \
                        (char*)(bufp) + i_ * 1024);                              \
        }                                                                        \
    }

    STAGE(xs[0], 0);
    __syncthreads();

    int buf = 0;
#pragma unroll 1
    for (int n = 0; n < 30; ++n) {
        if (n + 1 < 30) STAGE(xs[buf ^ 1], (n + 1) * 32);

        bf16x8 bfrag;
#pragma unroll
        for (int k = 0; k < 8; ++k) {
            const float v = *(const float*)(xs[buf] + (kb * 8 + k) * 256 + rbase);
            bfrag[k] = f2b(v);
        }
#pragma unroll
        for (int f = 0; f < 6; ++f) {
            const bf16x8 af = *(const bf16x8*)(wp + (size_t)f * 16 * CIN + n * 32);
            acc[f] = __builtin_amdgcn_mfma_f32_16x16x32_bf16(af, bfrag, acc[f], 0, 0, 0);
        }
        __syncthreads();
        buf ^= 1;
    }
#undef STAGE

    // epilogue: C/D col(px) = lane&15, row(o) = (lane>>4)*4 + r
    short* yp = yb + (size_t)b * COUT * PIX + px0 + pxl;
#pragma unroll
    for (int f = 0; f < 6; ++f) {
        const int o0 = f * 16 + (lane >> 4) * 4;
        const float4 bi = *(const float4*)(bias + o0);
        yp[(size_t)(o0 + 0) * PIX] = f2b(acc[f][0] + bi.x);
        yp[(size_t)(o0 + 1) * PIX] = f2b(acc[f][1] + bi.y);
        yp[(size_t)(o0 + 2) * PIX] = f2b(acc[f][2] + bi.z);
        yp[(size_t)(o0 + 3) * PIX] = f2b(acc[f][3] + bi.w);
    }
}

// ---------------------------------------------------------------------------
// Antialiased 58->56 triangle weights, tap indices mapped to the 56-grid
// (clamp(i-1,0,55) reproduces the replicate-padded ring).
__device__ __forceinline__ void rweights56(int o, int* idx, float* wt) {
    const float ratio = 58.0f / 56.0f;
    const float kinv  = 56.0f / 58.0f;
    const float sf = ((float)o + 0.5f) * ratio - 0.5f;
    const int f0 = (int)floorf(sf);
    float sum = 0.f;
#pragma unroll
    for (int t = 0; t < 4; ++t) {
        int i = f0 - 1 + t;
        float w = fmaxf(1.0f - fabsf(sf - (float)i) * kinv, 0.0f);
        if (i < 0 || i > 57) w = 0.0f;
        idx[t] = min(HH - 1, max(0, i - 1));
        wt[t] = w;
        sum += w;
    }
    const float inv = 1.0f / sum;
#pragma unroll
    for (int t = 0; t < 4; ++t) wt[t] *= inv;
}

// ---------------------------------------------------------------------------
// K2: one block per (b,co) plane. Stage the 10 gather channels (bf16) into
// LDS once (coalesced), compute 30-term global sum from LDS; 16-tap resize
// of the bf16 y plane read from global (L2-hot). out = blend.
__global__ __launch_bounds__(256)
void finalize(const float* __restrict__ x, const int* __restrict__ pad_hv,
              const int* __restrict__ idt, const short* __restrict__ yb,
              const float* __restrict__ alpha_p, float* __restrict__ out) {
    const int bc = blockIdx.x;          // b*96 + co
    const int co = bc % COUT;
    const int b  = bc / COUT;
    const int t  = threadIdx.x;

    __shared__ short xpl[10][PIX];      // 62720 B
    __shared__ int   ish[10], isv[10];
    __shared__ float fid[10];

    if (t < 10) {
        const int g = t / 5;
        const int k = t - g * 5;
        const int slot = co * NK_ + k;
        ish[t] = pad_hv[slot * 4 + g];
        isv[t] = pad_hv[slot * 4 + 2 + g];
        fid[t] = (idt[slot * 2 + g] >= 0) ? 1.f : 0.f;
    }

    {   // stage 10 channel planes as bf16
        const float* xb = x + (size_t)b * CIN * PIX;
#pragma unroll 1
        for (int p = 0; p < 10; ++p) {
            const int g  = (p < 5) ? 0 : 1;
            const int ic = g * (COUT * NK_) + co * NK_ + (p - g * 5);
            const float* src = xb + (size_t)ic * PIX;
            short* dst = xpl[p];
            for (int i = t; i < PIX / 4; i += 256) {
                const float4 v = *(const float4*)(src + i * 4);
                short4 s4;
                s4.x = f2b(v.x); s4.y = f2b(v.y); s4.z = f2b(v.z); s4.w = f2b(v.w);
                *(short4*)(dst + i * 4) = s4;
            }
        }
    }
    __syncthreads();

    const float alpha = alpha_p[0];
    const float ia = 1.0f - alpha;
    const short* ypl = yb + (size_t)bc * PIX;
    float* op = out + (size_t)bc * PIX;

#pragma unroll 1
    for (int px = t; px < PIX; px += 256) {
        const int h = (px * 18725) >> 20;     // px/56 for px<3136
        const int w = px - h * WW_;

        float accg = 0.f;
#pragma unroll
        for (int p = 0; p < 10; ++p) {
            const int jw = w + ish[p];
            const float mh = (jw >= -1 && jw <= WW_) ? 1.f : 0.f;
            accg += mh * b2f(xpl[p][h * WW_ + min(WW_ - 1, max(0, jw))]);

            const int iv = h + isv[p];
            const float mv = (iv >= -1 && iv <= HH) ? 1.f : 0.f;
            accg += mv * b2f(xpl[p][min(HH - 1, max(0, iv)) * WW_ + w]);

            accg += fid[p] * b2f(xpl[p][px]);
        }

        int ihx[4], iwx[4];
        float whv[4], wwv[4];
        rweights56(h, ihx, whv);
        rweights56(w, iwx, wwv);
        float accl = 0.f;
#pragma unroll
        for (int a = 0; a < 4; ++a) {
            const short* yr = ypl + ihx[a] * WW_;
            float rs = 0.f;
#pragma unroll
            for (int tt = 0; tt < 4; ++tt)
                rs = fmaf(wwv[tt], b2f(yr[iwx[tt]]), rs);
            accl = fmaf(whv[a], rs, accl);
        }

        op[px] = alpha * accg * (1.0f / 3.0f) + ia * accl;
    }
}

// ---------------------------------------------------------------------------
extern "C" void kernel_launch(void* const* d_in, const int* in_sizes, int n_in,
                              void* d_out, int out_size, void* d_ws, size_t ws_size,
                              hipStream_t stream) {
    const float* x      = (const float*)d_in[0];
    const int*   pad_hv = (const int*)d_in[1];
    const int*   idt    = (const int*)d_in[2];
    const float* lsc    = (const float*)d_in[3];
    const float* lbi    = (const float*)d_in[4];
    const float* pw     = (const float*)d_in[5];
    const float* alpha  = (const float*)d_in[6];
    float* out = (float*)d_out;

    float* ws   = (float*)d_ws;
    short* wb   = (short*)(ws + WB_OFF);
    float* bias = ws + BIAS_OFF;
    short* yb   = (short*)(ws + Y_OFF);

    prep_wb<<<(COUT * CIN + 255) / 256, 256, 0, stream>>>(pw, lsc, wb);
    prep_bias<<<1, 128, 0, stream>>>(pw, lbi, bias);
    conv_mfma<<<dim3(PIX / 64, B_), 256, 0, stream>>>(x, wb, bias, yb);
    finalize<<<B_ * COUT, 256, 0, stream>>>(x, pad_hv, idt, yb, alpha, out);
}

// Round 5
// 151.242 us; speedup vs baseline: 1.4339x; 1.4339x over previous
//
#include <hip/hip_runtime.h>
#include <hip/hip_bf16.h>
#include <cstdint>
#include <cstddef>

// Problem constants
#define B_    16
#define CIN   960
#define HH    56
#define WW_   56
#define GG    2
#define COUT  96
#define NK_   5
#define PIX   3136   // 56*56

// Workspace layout (float indices):
//   wb  (bf16 [96][960]) at 0 ; bias f32[96] at 46080 ; y bf16[16][96][3136] at 46208
#define WB_OFF   0
#define BIAS_OFF 46080
#define Y_OFF    46208

typedef __attribute__((ext_vector_type(8))) short bf16x8;
typedef __attribute__((ext_vector_type(4))) float f32x4;

__device__ __forceinline__ short f2b(float f) {
    union { float f; unsigned u; } c; c.f = f;
    unsigned r = (c.u + 0x7FFFu + ((c.u >> 16) & 1u)) >> 16;
    return (short)r;
}
__device__ __forceinline__ float b2f(short s) {
    union { unsigned u; float f; } c;
    c.u = ((unsigned)(unsigned short)s) << 16;
    return c.f;
}

#define GLOAD_LDS16(gp, lp)                                                        \
    __builtin_amdgcn_global_load_lds(                                              \
        (const __attribute__((address_space(1))) unsigned*)(gp),                   \
        (__attribute__((address_space(3))) unsigned*)(lp), 16, 0, 0)

#define WAITVM8() asm volatile("s_waitcnt vmcnt(8)" ::: "memory")
#define RBARRIER() asm volatile("s_barrier" ::: "memory")

// ---------------------------------------------------------------------------
__global__ void prep_wb(const float* __restrict__ pw, const float* __restrict__ sc,
                        short* __restrict__ wb) {
    int idx = blockIdx.x * 256 + threadIdx.x;   // o*960 + c
    if (idx >= COUT * CIN) return;
    int c = idx % CIN;
    wb[idx] = f2b(pw[idx] * (sc[c] + 1e-5f));
}

// bias_o[o] = sum_c proj_w[o][c] * local_bias[c]   (96 blocks x 1 wave)
__global__ void prep_bias(const float* __restrict__ pw, const float* __restrict__ bi,
                          float* __restrict__ bias) {
    const int o = blockIdx.x;
    const int l = threadIdx.x;
    float s = 0.f;
    for (int c = l; c < CIN; c += 64) s += pw[o * CIN + c] * bi[c];
#pragma unroll
    for (int off = 32; off; off >>= 1) s += __shfl_down(s, off);
    if (l == 0) bias[o] = s;
}

// ---------------------------------------------------------------------------
// K1: y[b,o,px] = sum_c W[o][c]*x[b,c,px]  (bias added in finalize; y bf16)
// 256 thr / 4 waves, 64 px x 96 out per block. 3-buffer LDS pipeline with
// counted vmcnt + raw s_barrier: prefetch survives the barrier (never vmcnt 0).
__global__ __launch_bounds__(256)
void conv_mfma(const float* __restrict__ x, const short* __restrict__ wb,
               short* __restrict__ yb) {
    const int tid  = threadIdx.x;
    const int lane = tid & 63;
    const int wv   = tid >> 6;
    const int b    = blockIdx.y;
    const int px0  = blockIdx.x * 64;

    __shared__ __align__(16) char xs[3][8192];   // [32ch][64px] fp32 each

    const float* xbase = x + (size_t)b * CIN * PIX + px0;

    const int pxl = wv * 16 + (lane & 15);   // local pixel 0..63
    const int kb  = lane >> 4;               // k-block 0..3
    const int rbase = (pxl * 4) ^ (kb << 6); // swizzled byte offset (verified r4)
    const short* const wp = wb + (size_t)(lane & 15) * CIN + kb * 8;

    f32x4 acc[6];
#pragma unroll
    for (int f = 0; f < 6; ++f) acc[f] = (f32x4){0.f, 0.f, 0.f, 0.f};

#define STAGE(bufp, c0)                                                          \
    {                                                                            \
        _Pragma("unroll")                                                        \
        for (int q = 0; q < 2; ++q) {                                            \
            const int i_  = wv * 2 + q;                                          \
            const int ch_ = (c0) + i_ * 4 + (lane >> 4);                         \
            const int px4 = (lane & 15) ^ (((i_ >> 1) & 3) << 2);                \
            GLOAD_LDS16(xbase + (size_t)ch_ * PIX + px4 * 4,                     \
                        (char*)(bufp) + i_ * 1024);                              \
        }                                                                        \
    }

    bf16x8 afA[6], afB[6];

    // prologue: chunks 0,1 staged; W(0) in afA
    STAGE(xs[0], 0);
#pragma unroll
    for (int f = 0; f < 6; ++f)
        afA[f] = *(const bf16x8*)(wp + (size_t)f * 16 * CIN);
    STAGE(xs[1], 32);

    // STEP(n): wait chunk n landed (leave <=8 newest in flight), barrier,
    // read B-frag, prefetch chunk n+2 + weights n+1, MFMA with current weights.
#define STEP(n, BI, BS, CUR, NXT)                                                \
    {                                                                            \
        WAITVM8();                                                               \
        RBARRIER();                                                              \
        bf16x8 bfrag;                                                            \
        _Pragma("unroll")                                                        \
        for (int k = 0; k < 8; ++k)                                              \
            bfrag[k] = f2b(*(const float*)(xs[BI] + (kb * 8 + k) * 256 + rbase));\
        if ((n) + 2 < 30) STAGE(xs[BS], ((n) + 2) * 32);                         \
        if ((n) + 1 < 30) {                                                      \
            _Pragma("unroll")                                                    \
            for (int f = 0; f < 6; ++f)                                          \
                NXT[f] = *(const bf16x8*)(wp + (size_t)f * 16 * CIN + ((n) + 1) * 32); \
        }                                                                        \
        _Pragma("unroll")                                                        \
        for (int f = 0; f < 6; ++f)                                              \
            acc[f] = __builtin_amdgcn_mfma_f32_16x16x32_bf16(CUR[f], bfrag, acc[f], 0, 0, 0); \
    }

#pragma unroll 1
    for (int mm = 0; mm < 5; ++mm) {
        const int n0 = mm * 6;                 // buffer cycle (3) x af cycle (2) align at 6
        STEP(n0 + 0, 0, 2, afA, afB);
        STEP(n0 + 1, 1, 0, afB, afA);
        STEP(n0 + 2, 2, 1, afA, afB);
        STEP(n0 + 3, 0, 2, afB, afA);
        STEP(n0 + 4, 1, 0, afA, afB);
        STEP(n0 + 5, 2, 1, afB, afA);
    }
#undef STEP
#undef STAGE

    // epilogue: C/D col(px) = lane&15, row(o) = (lane>>4)*4 + r
    short* yp = yb + (size_t)b * COUT * PIX + px0 + pxl;
#pragma unroll
    for (int f = 0; f < 6; ++f) {
        const int o0 = f * 16 + (lane >> 4) * 4;
#pragma unroll
        for (int r = 0; r < 4; ++r)
            yp[(size_t)(o0 + r) * PIX] = f2b(acc[f][r]);
    }
}

// ---------------------------------------------------------------------------
// Antialiased 58->56 triangle weights; tap indices mapped to the 56-grid
// (clamp(i-1,0,55) reproduces the replicate-padded ring).
__device__ __forceinline__ void rweights56(int o, short* idx, float* wt) {
    const float ratio = 58.0f / 56.0f;
    const float kinv  = 56.0f / 58.0f;
    const float sf = ((float)o + 0.5f) * ratio - 0.5f;
    const int f0 = (int)floorf(sf);
    float sum = 0.f;
#pragma unroll
    for (int t = 0; t < 4; ++t) {
        int i = f0 - 1 + t;
        float w = fmaxf(1.0f - fabsf(sf - (float)i) * kinv, 0.0f);
        if (i < 0 || i > 57) w = 0.0f;
        idx[t] = (short)min(HH - 1, max(0, i - 1));
        wt[t] = w;
        sum += w;
    }
    const float inv = 1.0f / sum;
#pragma unroll
    for (int t = 0; t < 4; ++t) wt[t] *= inv;
}

// ---------------------------------------------------------------------------
// K2: one block per (b,co) plane, 256 thr, lane-consecutive pixels.
// y plane staged bf16->f32 in LDS; resize weight tables in LDS; x gathers
// direct from global (plane-exclusive -> L2-hot after first touch).
__global__ __launch_bounds__(256)
void finalize(const float* __restrict__ x, const int* __restrict__ pad_hv,
              const int* __restrict__ idt, const short* __restrict__ yb,
              const float* __restrict__ bias, const float* __restrict__ alpha_p,
              float* __restrict__ out) {
    const int bc = blockIdx.x;          // b*96 + co
    const int co = bc % COUT;
    const int b  = bc / COUT;
    const int t  = threadIdx.x;

    __shared__ float  ylds[PIX];        // 12544 B
    __shared__ float4 wt4[56];          // resize weights (same table for h and w)
    __shared__ short4 id4[56];
    __shared__ int   ish[10], isv[10], ipl[10];
    __shared__ float fid[10];

    if (t < 10) {
        const int g = t / 5;
        const int k = t - g * 5;
        const int slot = co * NK_ + k;
        ish[t] = pad_hv[slot * 4 + g];
        isv[t] = pad_hv[slot * 4 + 2 + g];
        fid[t] = (idt[slot * 2 + g] >= 0) ? 1.f : 0.f;
        ipl[t] = (g * (COUT * NK_) + slot) * PIX;
    }
    if (t < 56) {
        short ii[4]; float ww[4];
        rweights56(t, ii, ww);
        wt4[t] = make_float4(ww[0], ww[1], ww[2], ww[3]);
        id4[t] = make_short4(ii[0], ii[1], ii[2], ii[3]);
    }
    {   // stage y plane as f32
        const short* yp = yb + (size_t)bc * PIX;
#pragma unroll 1
        for (int i = t; i < PIX / 4; i += 256) {
            const short4 s4 = *(const short4*)(yp + i * 4);
            *(float4*)(ylds + i * 4) =
                make_float4(b2f(s4.x), b2f(s4.y), b2f(s4.z), b2f(s4.w));
        }
    }
    __syncthreads();

    int   ish_r[10], isv_r[10], ipl_r[10];
    float fid_r[10];
#pragma unroll
    for (int p = 0; p < 10; ++p) {
        ish_r[p] = ish[p]; isv_r[p] = isv[p];
        ipl_r[p] = ipl[p]; fid_r[p] = fid[p];
    }

    const float alpha = alpha_p[0];
    const float ia    = 1.0f - alpha;
    const float bco   = bias[co];
    const float* xb = x + (size_t)b * CIN * PIX;
    float* op = out + (size_t)bc * PIX;

#pragma unroll 1
    for (int px = t; px < PIX; px += 256) {
        const int h = (px * 18725) >> 20;       // px/56
        const int w = px - h * WW_;
        const int hrow = px - w;                // h*56

        float accg = 0.f;
#pragma unroll
        for (int p = 0; p < 10; ++p) {
            const float* xc = xb + ipl_r[p];
            const int jw = w + ish_r[p];
            const float mh = (jw >= -1 && jw <= WW_) ? 1.f : 0.f;
            accg += mh * xc[hrow + min(WW_ - 1, max(0, jw))];

            const int iv = h + isv_r[p];
            const float mv = (iv >= -1 && iv <= HH) ? 1.f : 0.f;
            accg += mv * xc[min(HH - 1, max(0, iv)) * WW_ + w];

            accg += fid_r[p] * xc[px];
        }

        // separable antialiased resize from LDS (f32)
        const float4 ww4 = wt4[w];
        const short4 iw4 = id4[w];
        const float4 wh4 = wt4[h];
        const short4 ih4 = id4[h];
        float accl = 0.f;
#pragma unroll
        for (int a = 0; a < 4; ++a) {
            const int row = ((const short*)&ih4)[a] * WW_;
            const float* yr = ylds + row;
            float rs;
            rs = ww4.x * yr[iw4.x];
            rs = fmaf(ww4.y, yr[iw4.y], rs);
            rs = fmaf(ww4.z, yr[iw4.z], rs);
            rs = fmaf(ww4.w, yr[iw4.w], rs);
            accl = fmaf(((const float*)&wh4)[a], rs, accl);
        }
        accl += bco;   // resize weights sum to 1 -> bias commutes exactly

        op[px] = alpha * accg * (1.0f / 3.0f) + ia * accl;
    }
}

// ---------------------------------------------------------------------------
extern "C" void kernel_launch(void* const* d_in, const int* in_sizes, int n_in,
                              void* d_out, int out_size, void* d_ws, size_t ws_size,
                              hipStream_t stream) {
    const float* x      = (const float*)d_in[0];
    const int*   pad_hv = (const int*)d_in[1];
    const int*   idt    = (const int*)d_in[2];
    const float* lsc    = (const float*)d_in[3];
    const float* lbi    = (const float*)d_in[4];
    const float* pw     = (const float*)d_in[5];
    const float* alpha  = (const float*)d_in[6];
    float* out = (float*)d_out;

    float* ws   = (float*)d_ws;
    short* wb   = (short*)(ws + WB_OFF);
    float* bias = ws + BIAS_OFF;
    short* yb   = (short*)(ws + Y_OFF);

    prep_wb<<<(COUT * CIN + 255) / 256, 256, 0, stream>>>(pw, lsc, wb);
    prep_bias<<<COUT, 64, 0, stream>>>(pw, lbi, bias);
    conv_mfma<<<dim3(PIX / 64, B_), 256, 0, stream>>>(x, wb, yb);
    finalize<<<B_ * COUT, 256, 0, stream>>>(x, pad_hv, idt, yb, bias, alpha, out);
}

// Round 6
// 100.533 us; speedup vs baseline: 2.1571x; 1.5044x over previous
//
#include <hip/hip_runtime.h>
#include <hip/hip_bf16.h>
#include <cstdint>
#include <cstddef>

// Problem constants
#define B_    16
#define CIN   960
#define HH    56
#define WW_   56
#define GG    2
#define COUT  96
#define NK_   5
#define PIX   3136   // 56*56
#define NCH   30     // K-chunks of 32

// Workspace layout (float indices):
//   wf  (bf16 fragment-ordered [30*6*64][8]) at 0  (46080 floats)
//   bias f32[96] at 46080 ; y bf16[16][96][3136] at 46208
#define WF_OFF   0
#define BIAS_OFF 46080
#define Y_OFF    46208

typedef __attribute__((ext_vector_type(8))) short bf16x8;
typedef __attribute__((ext_vector_type(4))) float f32x4;

__device__ __forceinline__ short f2b(float f) {
    union { float f; unsigned u; } c; c.f = f;
    unsigned r = (c.u + 0x7FFFu + ((c.u >> 16) & 1u)) >> 16;
    return (short)r;
}
__device__ __forceinline__ float b2f(short s) {
    union { unsigned u; float f; } c;
    c.u = ((unsigned)(unsigned short)s) << 16;
    return c.f;
}

#define GLOAD_LDS16(gp, lp)                                                        \
    __builtin_amdgcn_global_load_lds(                                              \
        (const __attribute__((address_space(1))) unsigned*)(gp),                   \
        (__attribute__((address_space(3))) unsigned*)(lp), 16, 0, 0)

#define WAITVM8() asm volatile("s_waitcnt vmcnt(8)" ::: "memory")
#define RBARRIER() asm volatile("s_barrier" ::: "memory")

// ---------------------------------------------------------------------------
// K0a: fragment-ordered weights.
// wf[((n*6+f)*64 + lane)*8 + k] = bf16( pw[o][c]*(sc[c]+1e-5) )
//   with o = f*16 + (lane&15), c = n*32 + (lane>>4)*8 + k.
// A wave's fragment load for (n,f) is then one contiguous 1 KB dwordx4.
__global__ void prep_wb(const float* __restrict__ pw, const float* __restrict__ sc,
                        short* __restrict__ wf) {
    int idx = blockIdx.x * 256 + threadIdx.x;   // (n*6+f)*64 + lane
    if (idx >= NCH * 6 * 64) return;
    const int lane = idx & 63;
    const int nf   = idx >> 6;
    const int f    = nf % 6;
    const int n    = nf / 6;
    const int o    = f * 16 + (lane & 15);
    const int c0   = n * 32 + (lane >> 4) * 8;
    bf16x8 v;
#pragma unroll
    for (int k = 0; k < 8; ++k)
        v[k] = f2b(pw[o * CIN + c0 + k] * (sc[c0 + k] + 1e-5f));
    *(bf16x8*)(wf + (size_t)idx * 8) = v;
}

// bias_o[o] = sum_c proj_w[o][c] * local_bias[c]   (96 blocks x 1 wave)
__global__ void prep_bias(const float* __restrict__ pw, const float* __restrict__ bi,
                          float* __restrict__ bias) {
    const int o = blockIdx.x;
    const int l = threadIdx.x;
    float s = 0.f;
    for (int c = l; c < CIN; c += 64) s += pw[o * CIN + c] * bi[c];
#pragma unroll
    for (int off = 32; off; off >>= 1) s += __shfl_down(s, off);
    if (l == 0) bias[o] = s;
}

// ---------------------------------------------------------------------------
// K1: y[b,o,px] = sum_c W[o][c]*x[b,c,px]  (bias added in finalize; y bf16)
// 256 thr / 4 waves, 64 px x 96 out per block. 3-buffer LDS pipeline +
// 3-buffer register weight pipeline (distance 2), raw s_barrier, vmcnt(8):
// the newest step-group (2 stage + 6 coalesced weight loads) stays in flight.
__global__ __launch_bounds__(256)
void conv_mfma(const float* __restrict__ x, const short* __restrict__ wf,
               short* __restrict__ yb) {
    const int tid  = threadIdx.x;
    const int lane = tid & 63;
    const int wv   = tid >> 6;
    const int b    = blockIdx.y;
    const int px0  = blockIdx.x * 64;

    __shared__ __align__(16) char xs[3][8192];   // [32ch][64px] fp32 each

    const float* xbase = x + (size_t)b * CIN * PIX + px0;

    const int pxl = wv * 16 + (lane & 15);   // local pixel 0..63
    const int kb  = lane >> 4;               // k-block 0..3
    const int rbase = (pxl * 4) ^ (kb << 6); // swizzled byte offset (verified r4)
    const short* const wfl = wf + lane * 8;  // + (n*6+f)*512

    f32x4 acc[6];
#pragma unroll
    for (int f = 0; f < 6; ++f) acc[f] = (f32x4){0.f, 0.f, 0.f, 0.f};

#define STAGE(bufp, c0)                                                          \
    {                                                                            \
        _Pragma("unroll")                                                        \
        for (int q = 0; q < 2; ++q) {                                            \
            const int i_  = wv * 2 + q;                                          \
            const int ch_ = (c0) + i_ * 4 + (lane >> 4);                         \
            const int px4 = (lane & 15) ^ (((i_ >> 1) & 3) << 2);                \
            GLOAD_LDS16(xbase + (size_t)ch_ * PIX + px4 * 4,                     \
                        (char*)(bufp) + i_ * 1024);                              \
        }                                                                        \
    }

#define WLOAD(dst, n2)                                                           \
    {                                                                            \
        _Pragma("unroll")                                                        \
        for (int f = 0; f < 6; ++f)                                              \
            dst[f] = *(const bf16x8*)(wfl + ((n2) * 6 + f) * 512);               \
    }

    bf16x8 afA[6], afB[6], afC[6];

    // prologue: chunks 0,1 staged; weights 0,1 in afA/afB
    STAGE(xs[0], 0);
    STAGE(xs[1], 32);
    WLOAD(afA, 0);
    WLOAD(afB, 1);

    // STEP(n): wait group(n-2) landed (keep newest 8 = group(n-1) in flight),
    // barrier, read B-frag from xs[BI], prefetch chunk/weights n+2, MFMA(CUR).
#define STEP(n, BI, BS, CUR, NXT)                                                \
    {                                                                            \
        WAITVM8();                                                               \
        RBARRIER();                                                              \
        bf16x8 bfrag;                                                            \
        _Pragma("unroll")                                                        \
        for (int k = 0; k < 8; ++k)                                              \
            bfrag[k] = f2b(*(const float*)(xs[BI] + (kb * 8 + k) * 256 + rbase));\
        if ((n) + 2 < NCH) {                                                     \
            STAGE(xs[BS], ((n) + 2) * 32);                                       \
            WLOAD(NXT, (n) + 2);                                                 \
        }                                                                        \
        _Pragma("unroll")                                                        \
        for (int f = 0; f < 6; ++f)                                              \
            acc[f] = __builtin_amdgcn_mfma_f32_16x16x32_bf16(CUR[f], bfrag, acc[f], 0, 0, 0); \
    }

#pragma unroll 1
    for (int mm = 0; mm < 10; ++mm) {
        const int n0 = mm * 3;
        STEP(n0 + 0, 0, 2, afA, afC);
        STEP(n0 + 1, 1, 0, afB, afA);
        STEP(n0 + 2, 2, 1, afC, afB);
    }
#undef STEP
#undef WLOAD
#undef STAGE

    // epilogue: C/D col(px) = lane&15, row(o) = (lane>>4)*4 + r
    short* yp = yb + (size_t)b * COUT * PIX + px0 + pxl;
#pragma unroll
    for (int f = 0; f < 6; ++f) {
        const int o0 = f * 16 + (lane >> 4) * 4;
#pragma unroll
        for (int r = 0; r < 4; ++r)
            yp[(size_t)(o0 + r) * PIX] = f2b(acc[f][r]);
    }
}

// ---------------------------------------------------------------------------
// Antialiased 58->56 triangle weights; tap indices mapped to the 56-grid
// (clamp(i-1,0,55) reproduces the replicate-padded ring).
__device__ __forceinline__ void rweights56(int o, short* idx, float* wt) {
    const float ratio = 58.0f / 56.0f;
    const float kinv  = 56.0f / 58.0f;
    const float sf = ((float)o + 0.5f) * ratio - 0.5f;
    const int f0 = (int)floorf(sf);
    float sum = 0.f;
#pragma unroll
    for (int t = 0; t < 4; ++t) {
        int i = f0 - 1 + t;
        float w = fmaxf(1.0f - fabsf(sf - (float)i) * kinv, 0.0f);
        if (i < 0 || i > 57) w = 0.0f;
        idx[t] = (short)min(HH - 1, max(0, i - 1));
        wt[t] = w;
        sum += w;
    }
    const float inv = 1.0f / sum;
#pragma unroll
    for (int t = 0; t < 4; ++t) wt[t] *= inv;
}

// ---------------------------------------------------------------------------
// K2: one block per (b,co) plane, 256 thr, lane-consecutive pixels.
// y plane staged bf16->f32 in LDS; resize weight tables in LDS; x gathers
// direct from global (plane-exclusive -> L2-hot after first touch).
__global__ __launch_bounds__(256)
void finalize(const float* __restrict__ x, const int* __restrict__ pad_hv,
              const int* __restrict__ idt, const short* __restrict__ yb,
              const float* __restrict__ bias, const float* __restrict__ alpha_p,
              float* __restrict__ out) {
    const int bc = blockIdx.x;          // b*96 + co
    const int co = bc % COUT;
    const int b  = bc / COUT;
    const int t  = threadIdx.x;

    __shared__ float  ylds[PIX];        // 12544 B
    __shared__ float4 wt4[56];
    __shared__ short4 id4[56];
    __shared__ int   ish[10], isv[10], ipl[10];
    __shared__ float fid[10];

    if (t < 10) {
        const int g = t / 5;
        const int k = t - g * 5;
        const int slot = co * NK_ + k;
        ish[t] = pad_hv[slot * 4 + g];
        isv[t] = pad_hv[slot * 4 + 2 + g];
        fid[t] = (idt[slot * 2 + g] >= 0) ? 1.f : 0.f;
        ipl[t] = (g * (COUT * NK_) + slot) * PIX;
    }
    if (t < 56) {
        short ii[4]; float ww[4];
        rweights56(t, ii, ww);
        wt4[t] = make_float4(ww[0], ww[1], ww[2], ww[3]);
        id4[t] = make_short4(ii[0], ii[1], ii[2], ii[3]);
    }
    {   // stage y plane as f32
        const short* yp = yb + (size_t)bc * PIX;
#pragma unroll 1
        for (int i = t; i < PIX / 4; i += 256) {
            const short4 s4 = *(const short4*)(yp + i * 4);
            *(float4*)(ylds + i * 4) =
                make_float4(b2f(s4.x), b2f(s4.y), b2f(s4.z), b2f(s4.w));
        }
    }
    __syncthreads();

    int   ish_r[10], isv_r[10], ipl_r[10];
    float fid_r[10];
#pragma unroll
    for (int p = 0; p < 10; ++p) {
        ish_r[p] = ish[p]; isv_r[p] = isv[p];
        ipl_r[p] = ipl[p]; fid_r[p] = fid[p];
    }

    const float alpha = alpha_p[0];
    const float ia    = 1.0f - alpha;
    const float bco   = bias[co];
    const float* xb = x + (size_t)b * CIN * PIX;
    float* op = out + (size_t)bc * PIX;

#pragma unroll 1
    for (int px = t; px < PIX; px += 256) {
        const int h = (px * 18725) >> 20;       // px/56
        const int w = px - h * WW_;
        const int hrow = px - w;                // h*56

        float accg = 0.f;
#pragma unroll
        for (int p = 0; p < 10; ++p) {
            const float* xc = xb + ipl_r[p];
            const int jw = w + ish_r[p];
            const float mh = (jw >= -1 && jw <= WW_) ? 1.f : 0.f;
            accg += mh * xc[hrow + min(WW_ - 1, max(0, jw))];

            const int iv = h + isv_r[p];
            const float mv = (iv >= -1 && iv <= HH) ? 1.f : 0.f;
            accg += mv * xc[min(HH - 1, max(0, iv)) * WW_ + w];

            accg += fid_r[p] * xc[px];
        }

        const float4 ww4 = wt4[w];
        const short4 iw4 = id4[w];
        const float4 wh4 = wt4[h];
        const short4 ih4 = id4[h];
        float accl = 0.f;
#pragma unroll
        for (int a = 0; a < 4; ++a) {
            const int row = ((const short*)&ih4)[a] * WW_;
            const float* yr = ylds + row;
            float rs;
            rs = ww4.x * yr[iw4.x];
            rs = fmaf(ww4.y, yr[iw4.y], rs);
            rs = fmaf(ww4.z, yr[iw4.z], rs);
            rs = fmaf(ww4.w, yr[iw4.w], rs);
            accl = fmaf(((const float*)&wh4)[a], rs, accl);
        }
        accl += bco;

        op[px] = alpha * accg * (1.0f / 3.0f) + ia * accl;
    }
}

// ---------------------------------------------------------------------------
extern "C" void kernel_launch(void* const* d_in, const int* in_sizes, int n_in,
                              void* d_out, int out_size, void* d_ws, size_t ws_size,
                              hipStream_t stream) {
    const float* x      = (const float*)d_in[0];
    const int*   pad_hv = (const int*)d_in[1];
    const int*   idt    = (const int*)d_in[2];
    const float* lsc    = (const float*)d_in[3];
    const float* lbi    = (const float*)d_in[4];
    const float* pw     = (const float*)d_in[5];
    const float* alpha  = (const float*)d_in[6];
    float* out = (float*)d_out;

    float* ws   = (float*)d_ws;
    short* wf   = (short*)(ws + WF_OFF);
    float* bias = ws + BIAS_OFF;
    short* yb   = (short*)(ws + Y_OFF);

    prep_wb<<<(NCH * 6 * 64 + 255) / 256, 256, 0, stream>>>(pw, lsc, wf);
    prep_bias<<<COUT, 64, 0, stream>>>(pw, lbi, bias);
    conv_mfma<<<dim3(PIX / 64, B_), 256, 0, stream>>>(x, wf, yb);
    finalize<<<B_ * COUT, 256, 0, stream>>>(x, pad_hv, idt, yb, bias, alpha, out);
}

// Round 8
// 93.502 us; speedup vs baseline: 2.3193x; 1.0752x over previous
//
#include <hip/hip_runtime.h>
#include <hip/hip_bf16.h>
#include <cstdint>
#include <cstddef>

// Problem constants
#define B_    16
#define CIN   960
#define HH    56
#define WW_   56
#define GG    2
#define COUT  96
#define NK_   5
#define PIX   3136   // 56*56
#define NCH   30     // K-chunks of 32

// Workspace layout (float indices):
//   wf  bf16 fragment-ordered, PADDED: [NCH][8192 B] (frags in first 6144 B)
//        -> 30*8192 B = 61440 floats
//   bias f32[96] at 61440 ; y bf16[16][96][3136] at 61568
#define WF_OFF   0
#define BIAS_OFF 61440
#define Y_OFF    61568

typedef __attribute__((ext_vector_type(8))) short bf16x8;
typedef __attribute__((ext_vector_type(4))) float f32x4;

__device__ __forceinline__ short f2b(float f) {
    union { float f; unsigned u; } c; c.f = f;
    unsigned r = (c.u + 0x7FFFu + ((c.u >> 16) & 1u)) >> 16;
    return (short)r;
}
__device__ __forceinline__ float b2f(short s) {
    union { unsigned u; float f; } c;
    c.u = ((unsigned)(unsigned short)s) << 16;
    return c.f;
}

#define GLOAD_LDS16(gp, lp)                                                        \
    __builtin_amdgcn_global_load_lds(                                              \
        (const __attribute__((address_space(1))) unsigned*)(gp),                   \
        (__attribute__((address_space(3))) unsigned*)(lp), 16, 0, 0)

// ---------------------------------------------------------------------------
// K0a: fragment-ordered weights, padded per chunk.
// byte dest = n*8192 + (f*64 + lane)*16 ; content lane holds
//   o = f*16 + (lane&15), c = n*32 + (lane>>4)*8 + k  (k = 0..7, bf16x8).
__global__ void prep_wb(const float* __restrict__ pw, const float* __restrict__ sc,
                        short* __restrict__ wf) {
    int idx = blockIdx.x * 256 + threadIdx.x;   // (n*6+f)*64 + lane
    if (idx >= NCH * 6 * 64) return;
    const int lane = idx & 63;
    const int nf   = idx >> 6;
    const int f    = nf % 6;
    const int n    = nf / 6;
    const int o    = f * 16 + (lane & 15);
    const int c0   = n * 32 + (lane >> 4) * 8;
    bf16x8 v;
#pragma unroll
    for (int k = 0; k < 8; ++k)
        v[k] = f2b(pw[o * CIN + c0 + k] * (sc[c0 + k] + 1e-5f));
    *(bf16x8*)((char*)wf + (size_t)n * 8192 + (f * 64 + lane) * 16) = v;
}

// bias_o[o] = sum_c proj_w[o][c] * local_bias[c]   (96 blocks x 1 wave)
__global__ void prep_bias(const float* __restrict__ pw, const float* __restrict__ bi,
                          float* __restrict__ bias) {
    const int o = blockIdx.x;
    const int l = threadIdx.x;
    float s = 0.f;
    for (int c = l; c < CIN; c += 64) s += pw[o * CIN + c] * bi[c];
#pragma unroll
    for (int off = 32; off; off >>= 1) s += __shfl_down(s, off);
    if (l == 0) bias[o] = s;
}

// ---------------------------------------------------------------------------
// K1: y[b,o,px] = sum_c W[o][c]*x[b,c,px]  (bias added in finalize; y bf16)
// 512 thr / 8 waves = 2M x 4N: wave (m = wv>>2, n = wv&3) computes
// o in [m*48, m*48+48) x px-tile n (16 px). Per step per wave: 2 VMEM issues
// (x gload_lds16 + W gload_lds16, both 1024 B/wave), 3 ds_read_b128 (A),
// 8 ds_read_b32 (B), 3 MFMA. 3-buffer pipeline, raw s_barrier, vmcnt(2)
// (final step vmcnt(0)).
//
// LDS x layout: byte = ch*256 + G*64 + (px&15)*4, G = (px>>4) ^ S(ch),
// S(ch) = (ch>>3)&3. Write side (lane-linear gload_lds dest) stores source
// px-group s ^ S at slot s; read asks slot n ^ S -> content group n.
__global__ __launch_bounds__(512)
void conv_mfma(const float* __restrict__ x, const short* __restrict__ wf,
               short* __restrict__ yb) {
    const int tid  = threadIdx.x;
    const int lane = tid & 63;
    const int wv   = tid >> 6;          // 0..7
    const int m    = wv >> 2;           // o-half
    const int n    = wv & 3;            // px tile
    const int b    = blockIdx.y;
    const int px0  = blockIdx.x * 64;

    __shared__ __align__(16) char xsb[3 * 8192];   // x chunks [32ch][64px] f32
    __shared__ __align__(16) char wlb[3 * 8192];   // W chunks (6 frags + pad)

    const float* xbase = x + (size_t)b * CIN * PIX + px0;
    const char*  wfB   = (const char*)wf;

    // staging constants (one x-DMA + one W-DMA per wave per chunk)
    const int sch  = wv * 4 + (lane >> 4);               // channel within chunk
    const int sS   = (wv >> 1) & 3;                      // == (sch>>3)&3
    const int soff = (((lane >> 2) & 3) ^ sS) * 16 + (lane & 3) * 4;  // src px (floats)
    const int wsub = wv * 1024 + lane * 16;              // W copy offset (bytes)

    // compute constants
    const int kb    = lane >> 4;
    const int bcol  = (lane & 15) * 4;
    const int bslot = ((n ^ kb) & 3) * 64;
    const int babs  = kb * 2048 + bslot + bcol;          // + k*256, + BI*8192
    const int abase = m * 3072 + lane * 16;              // + fl*1024, + BI*8192

    f32x4 acc0 = {0.f, 0.f, 0.f, 0.f};
    f32x4 acc1 = {0.f, 0.f, 0.f, 0.f};
    f32x4 acc2 = {0.f, 0.f, 0.f, 0.f};

#define STAGE(BS, c0)                                                            \
    {                                                                            \
        GLOAD_LDS16(xbase + (size_t)((c0) + sch) * PIX + soff,                   \
                    xsb + (BS) * 8192 + wv * 1024);                              \
        GLOAD_LDS16(wfB + (size_t)((c0) >> 5) * 8192 + wsub,                     \
                    wlb + (BS) * 8192 + wv * 1024);                              \
    }

    // prologue: chunks 0,1 in flight (4 VMEM/wave)
    STAGE(0, 0);
    STAGE(1, 32);

    // STEP(n): wait chunk n landed (keep newest 2 = chunk n+1 in flight),
    // barrier, read A/B frags from buf BI, prefetch chunk n+2, 3 MFMAs.
#define STEP(n_, BI, BS, VM)                                                     \
    {                                                                            \
        asm volatile("s_waitcnt vmcnt(" #VM ")" ::: "memory");                   \
        asm volatile("s_barrier" ::: "memory");                                  \
        bf16x8 bfrag;                                                            \
        _Pragma("unroll")                                                        \
        for (int k = 0; k < 8; ++k)                                              \
            bfrag[k] = f2b(*(const float*)(xsb + (BI) * 8192 + babs + k * 256)); \
        const bf16x8 af0 = *(const bf16x8*)(wlb + (BI) * 8192 + abase);          \
        const bf16x8 af1 = *(const bf16x8*)(wlb + (BI) * 8192 + abase + 1024);   \
        const bf16x8 af2 = *(const bf16x8*)(wlb + (BI) * 8192 + abase + 2048);   \
        if ((n_) + 2 < NCH) STAGE(BS, ((n_) + 2) * 32);                          \
        acc0 = __builtin_amdgcn_mfma_f32_16x16x32_bf16(af0, bfrag, acc0, 0,0,0); \
        acc1 = __builtin_amdgcn_mfma_f32_16x16x32_bf16(af1, bfrag, acc1, 0,0,0); \
        acc2 = __builtin_amdgcn_mfma_f32_16x16x32_bf16(af2, bfrag, acc2, 0,0,0); \
    }

#pragma unroll 1
    for (int mm = 0; mm < 9; ++mm) {
        const int n0 = mm * 3;
        STEP(n0 + 0, 0, 2, 2);
        STEP(n0 + 1, 1, 0, 2);
        STEP(n0 + 2, 2, 1, 2);
    }
    STEP(27, 0, 2, 2);
    STEP(28, 1, 0, 2);
    STEP(29, 2, 1, 0);   // drain: the tail chunk must actually land
#undef STEP
#undef STAGE

    // epilogue: C/D col(px) = lane&15, row(o) = (lane>>4)*4 + r
    short* yp = yb + (size_t)b * COUT * PIX + px0 + n * 16 + (lane & 15);
    const int o0 = m * 48 + (lane >> 4) * 4;
#pragma unroll
    for (int r = 0; r < 4; ++r) yp[(size_t)(o0 +      r) * PIX] = f2b(acc0[r]);
#pragma unroll
    for (int r = 0; r < 4; ++r) yp[(size_t)(o0 + 16 + r) * PIX] = f2b(acc1[r]);
#pragma unroll
    for (int r = 0; r < 4; ++r) yp[(size_t)(o0 + 32 + r) * PIX] = f2b(acc2[r]);
}

// ---------------------------------------------------------------------------
// Antialiased 58->56 triangle weights; tap indices mapped to the 56-grid
// (clamp(i-1,0,55) reproduces the replicate-padded ring).
__device__ __forceinline__ void rweights56(int o, short* idx, float* wt) {
    const float ratio = 58.0f / 56.0f;
    const float kinv  = 56.0f / 58.0f;
    const float sf = ((float)o + 0.5f) * ratio - 0.5f;
    const int f0 = (int)floorf(sf);
    float sum = 0.f;
#pragma unroll
    for (int t = 0; t < 4; ++t) {
        int i = f0 - 1 + t;
        float w = fmaxf(1.0f - fabsf(sf - (float)i) * kinv, 0.0f);
        if (i < 0 || i > 57) w = 0.0f;
        idx[t] = (short)min(HH - 1, max(0, i - 1));
        wt[t] = w;
        sum += w;
    }
    const float inv = 1.0f / sum;
#pragma unroll
    for (int t = 0; t < 4; ++t) wt[t] *= inv;
}

// ---------------------------------------------------------------------------
// K2: one block per (b,co) plane, 256 thr, lane-consecutive pixels.
// y plane staged bf16->f32 in LDS; resize weight tables in LDS; x gathers
// direct from global.
__global__ __launch_bounds__(256)
void finalize(const float* __restrict__ x, const int* __restrict__ pad_hv,
              const int* __restrict__ idt, const short* __restrict__ yb,
              const float* __restrict__ bias, const float* __restrict__ alpha_p,
              float* __restrict__ out) {
    const int bc = blockIdx.x;          // b*96 + co
    const int co = bc % COUT;
    const int b  = bc / COUT;
    const int t  = threadIdx.x;

    __shared__ float  ylds[PIX];        // 12544 B
    __shared__ float4 wt4[56];
    __shared__ short4 id4[56];
    __shared__ int   ish[10], isv[10], ipl[10];
    __shared__ float fid[10];

    if (t < 10) {
        const int g = t / 5;
        const int k = t - g * 5;
        const int slot = co * NK_ + k;
        ish[t] = pad_hv[slot * 4 + g];
        isv[t] = pad_hv[slot * 4 + 2 + g];
        fid[t] = (idt[slot * 2 + g] >= 0) ? 1.f : 0.f;
        ipl[t] = (g * (COUT * NK_) + slot) * PIX;
    }
    if (t < 56) {
        short ii[4]; float ww[4];
        rweights56(t, ii, ww);
        wt4[t] = make_float4(ww[0], ww[1], ww[2], ww[3]);
        id4[t] = make_short4(ii[0], ii[1], ii[2], ii[3]);
    }
    {   // stage y plane as f32
        const short* yp = yb + (size_t)bc * PIX;
#pragma unroll 1
        for (int i = t; i < PIX / 4; i += 256) {
            const short4 s4 = *(const short4*)(yp + i * 4);
            *(float4*)(ylds + i * 4) =
                make_float4(b2f(s4.x), b2f(s4.y), b2f(s4.z), b2f(s4.w));
        }
    }
    __syncthreads();

    int   ish_r[10], isv_r[10], ipl_r[10];
    float fid_r[10];
#pragma unroll
    for (int p = 0; p < 10; ++p) {
        ish_r[p] = ish[p]; isv_r[p] = isv[p];
        ipl_r[p] = ipl[p]; fid_r[p] = fid[p];
    }

    const float alpha = alpha_p[0];
    const float ia    = 1.0f - alpha;
    const float bco   = bias[co];
    const float* xb = x + (size_t)b * CIN * PIX;
    float* op = out + (size_t)bc * PIX;

#pragma unroll 1
    for (int px = t; px < PIX; px += 256) {
        const int h = (px * 18725) >> 20;       // px/56
        const int w = px - h * WW_;
        const int hrow = px - w;                // h*56

        float accg = 0.f;
#pragma unroll
        for (int p = 0; p < 10; ++p) {
            const float* xc = xb + ipl_r[p];
            const int jw = w + ish_r[p];
            const float mh = (jw >= -1 && jw <= WW_) ? 1.f : 0.f;
            accg += mh * xc[hrow + min(WW_ - 1, max(0, jw))];

            const int iv = h + isv_r[p];
            const float mv = (iv >= -1 && iv <= HH) ? 1.f : 0.f;
            accg += mv * xc[min(HH - 1, max(0, iv)) * WW_ + w];

            accg += fid_r[p] * xc[px];
        }

        const float4 ww4 = wt4[w];
        const short4 iw4 = id4[w];
        const float4 wh4 = wt4[h];
        const short4 ih4 = id4[h];
        float accl = 0.f;
#pragma unroll
        for (int a = 0; a < 4; ++a) {
            const int row = ((const short*)&ih4)[a] * WW_;
            const float* yr = ylds + row;
            float rs;
            rs = ww4.x * yr[iw4.x];
            rs = fmaf(ww4.y, yr[iw4.y], rs);
            rs = fmaf(ww4.z, yr[iw4.z], rs);
            rs = fmaf(ww4.w, yr[iw4.w], rs);
            accl = fmaf(((const float*)&wh4)[a], rs, accl);
        }
        accl += bco;

        op[px] = alpha * accg * (1.0f / 3.0f) + ia * accl;
    }
}

// ---------------------------------------------------------------------------
extern "C" void kernel_launch(void* const* d_in, const int* in_sizes, int n_in,
                              void* d_out, int out_size, void* d_ws, size_t ws_size,
                              hipStream_t stream) {
    const float* x      = (const float*)d_in[0];
    const int*   pad_hv = (const int*)d_in[1];
    const int*   idt    = (const int*)d_in[2];
    const float* lsc    = (const float*)d_in[3];
    const float* lbi    = (const float*)d_in[4];
    const float* pw     = (const float*)d_in[5];
    const float* alpha  = (const float*)d_in[6];
    float* out = (float*)d_out;

    float* ws   = (float*)d_ws;
    short* wf   = (short*)(ws + WF_OFF);
    float* bias = ws + BIAS_OFF;
    short* yb   = (short*)(ws + Y_OFF);

    prep_wb<<<(NCH * 6 * 64 + 255) / 256, 256, 0, stream>>>(pw, lsc, wf);
    prep_bias<<<COUT, 64, 0, stream>>>(pw, lbi, bias);
    conv_mfma<<<dim3(PIX / 64, B_), 512, 0, stream>>>(x, wf, yb);
    finalize<<<B_ * COUT, 256, 0, stream>>>(x, pad_hv, idt, yb, bias, alpha, out);
}